// Round 6
// baseline (319.929 us; speedup 1.0000x reference)
//
#include <hip/hip_runtime.h>
#include <hip/hip_bf16.h>

#define D 1024      // in_features
#define E 64        // num experts
#define TPB 256     // threads per block (4 waves)
#define TOKS 16     // tokens per block (shared by all 4 waves)
#define KC 64       // k per chunk (2 MFMA k-steps)
#define CPW 4       // chunks per wave (4-way K-split: 4 waves x 4 x 64 = 1024)
#define AP 68       // padded LDS row in floats (272 B, 16B-aligned, 2-way banks)

typedef __attribute__((ext_vector_type(8))) short bf16x8;
typedef __attribute__((ext_vector_type(4))) float f32x4;
typedef __attribute__((ext_vector_type(4))) int i32x4;
typedef __attribute__((ext_vector_type(4))) unsigned short u16x4;

__device__ __forceinline__ unsigned short bf16_rne(float f) {
    unsigned u = __builtin_bit_cast(unsigned, f);
    u += 0x7fffu + ((u >> 16) & 1u);
    return (unsigned short)(u >> 16);
}
__device__ __forceinline__ float bf16_as_f(unsigned short h) {
    unsigned u = ((unsigned)h) << 16;
    return __builtin_bit_cast(float, u);
}
__device__ __forceinline__ void split_hi_lo(float v, unsigned short& h, unsigned short& l) {
    h = bf16_rne(v);
    l = bf16_rne(v - bf16_as_f(h));
}

// ---- pre-kernel: split W into hi/lo bf16 planes, CHUNK-MAJOR (r5-verified) ----
// plane[c][e][kk] (shorts): each chunk c is 8 KB contiguous
__global__ __launch_bounds__(256) void wsplit_kernel(const float* __restrict__ W,
        unsigned short* __restrict__ whi, unsigned short* __restrict__ wlo) {
    int g = blockIdx.x * 256 + threadIdx.x;   // 16384 threads x 4 elems
    int e = g >> 8;
    int k = (g & 255) * 4;
    int c = k >> 6, kk = k & 63;
    f32x4 w = *(const f32x4*)(W + (size_t)g * 4);
    u16x4 h, l;
#pragma unroll
    for (int j = 0; j < 4; ++j) {
        unsigned short hh, ll;
        split_hi_lo(w[j], hh, ll);
        h[j] = hh; l[j] = ll;
    }
    size_t o = (size_t)c * (E * KC) + e * KC + kk;
    *(u16x4*)(whi + o) = h;
    *(u16x4*)(wlo + o) = l;
}

// Barrier-free K-split router: 4 waves x 4 chunks, B-frags direct from
// chunk-major global planes, A via wave-private LDS reorder, one barrier total.
__global__ __launch_bounds__(TPB, 4) void router_kernel(
        const float* __restrict__ x,
        const unsigned short* __restrict__ whi,
        const unsigned short* __restrict__ wlo,
        const float* __restrict__ bias,
        float* __restrict__ out, int T) {
    // Per-wave region: A-chunk staging [16][AP] floats, reused (same wave only)
    // as partial-logit store [16][AP] after the wave's k-loop finishes.
    __shared__ __align__(16) float R[4][TOKS * AP];   // 17408 B
    __shared__ float sbias[E];

    const int tid  = threadIdx.x;
    const int lane = tid & 63;
    const int wid  = tid >> 6;
    const int n    = lane & 15;    // MFMA m/n index
    const int q    = lane >> 4;    // MFMA quad -> k offset q*8
    const int t0   = blockIdx.x * TOKS;

    if (tid < E) sbias[tid] = bias[tid];

    f32x4 acc[4];
#pragma unroll
    for (int i = 0; i < 4; ++i) acc[i] = (f32x4){0.f, 0.f, 0.f, 0.f};

    // ---- contiguous A loads within this wave's k-window ----
    const float* abase = x + (size_t)t0 * D + wid * (CPW * KC);
    const int ar = lane >> 4;            // row subgroup
    const int ac = (lane & 15) * 4;      // float col in 64-float slice
    f32x4 aA[4], aB[4];
    auto load_a = [&](int cl, f32x4* v) {
#pragma unroll
        for (int i = 0; i < 4; ++i)
            v[i] = *(const f32x4*)(abase + (size_t)(i * 4 + ar) * D + cl * KC + ac);
    };
    auto write_a = [&](const f32x4* v) {
#pragma unroll
        for (int i = 0; i < 4; ++i)
            *(f32x4*)&R[wid][(i * 4 + ar) * AP + ac] = v[i];
    };

    load_a(0, aA);

    for (int cl = 0; cl < CPW; ++cl) {
        write_a(aA);                       // wave-private LDS, no barrier
        load_a((cl + 1) & 3, aB);          // next-chunk prefetch (last iter harmless)
        const size_t cb = (size_t)(wid * CPW + cl) * (E * KC);   // chunk base (shorts)

#pragma unroll
        for (int s = 0; s < 2; ++s) {
            const float* ap = &R[wid][n * AP + s * 32 + q * 8];
            f32x4 a0 = ((const f32x4*)ap)[0];
            f32x4 a1 = ((const f32x4*)ap)[1];
            unsigned short ah[8], al[8];
#pragma unroll
            for (int j = 0; j < 4; ++j) {
                split_hi_lo(a0[j], ah[j],     al[j]);
                split_hi_lo(a1[j], ah[4 + j], al[4 + j]);
            }
            bf16x8 ahv, alv;
#pragma unroll
            for (int j = 0; j < 8; ++j) { ahv[j] = (short)ah[j]; alv[j] = (short)al[j]; }
            const size_t fo = cb + (size_t)n * KC + s * 32 + q * 8;
#pragma unroll
            for (int nt = 0; nt < 4; ++nt) {
                const size_t o = fo + (size_t)(nt * 16) * KC;
                const bf16x8 bh = __builtin_bit_cast(bf16x8, *(const i32x4*)(whi + o));
                const bf16x8 bl = __builtin_bit_cast(bf16x8, *(const i32x4*)(wlo + o));
                acc[nt] = __builtin_amdgcn_mfma_f32_16x16x32_bf16(ahv, bh, acc[nt], 0, 0, 0);
                acc[nt] = __builtin_amdgcn_mfma_f32_16x16x32_bf16(alv, bh, acc[nt], 0, 0, 0);
                acc[nt] = __builtin_amdgcn_mfma_f32_16x16x32_bf16(ahv, bl, acc[nt], 0, 0, 0);
            }
        }
#pragma unroll
        for (int i = 0; i < 4; ++i) aA[i] = aB[i];
    }

    // ---- partial logits into this wave's own region (safe: own reads done) ----
#pragma unroll
    for (int nt = 0; nt < 4; ++nt) {
#pragma unroll
        for (int r = 0; r < 4; ++r) {
            // C/D layout: col = lane&15, row = (lane>>4)*4 + reg
            R[wid][(q * 4 + r) * AP + nt * 16 + n] = acc[nt][r];
        }
    }
    __syncthreads();

    // ---- reduce 4 partials + bias, softmax + top-2 (r1-verified scan) ----
    if (tid < TOKS) {
        float lg[E];
#pragma unroll
        for (int j = 0; j < 16; ++j) {
            f32x4 v0 = *(const f32x4*)&R[0][tid * AP + j * 4];
            f32x4 v1 = *(const f32x4*)&R[1][tid * AP + j * 4];
            f32x4 v2 = *(const f32x4*)&R[2][tid * AP + j * 4];
            f32x4 v3 = *(const f32x4*)&R[3][tid * AP + j * 4];
#pragma unroll
            for (int u = 0; u < 4; ++u)
                lg[j * 4 + u] = v0[u] + v1[u] + v2[u] + v3[u] + sbias[j * 4 + u];
        }
        float m1 = -3.4e38f, m2 = -3.4e38f;
        int i1 = 0, i2 = 0;
#pragma unroll
        for (int e = 0; e < E; ++e) {
            float v = lg[e];
            if (v > m1) { m2 = m1; i2 = i1; m1 = v; i1 = e; }
            else if (v > m2) { m2 = v; i2 = e; }
        }
        float Z = 0.f;
#pragma unroll
        for (int e = 0; e < E; ++e) Z += __expf(lg[e] - m1);
        float inv = 1.f / Z;
        int gt = t0 + tid;
        out[(size_t)gt * 2]     = inv;
        out[(size_t)gt * 2 + 1] = __expf(m2 - m1) * inv;
        float* oi = out + (size_t)T * 2;
        oi[(size_t)gt * 2]     = (float)i1;   // indices stored as float values
        oi[(size_t)gt * 2 + 1] = (float)i2;
    }
}

extern "C" void kernel_launch(void* const* d_in, const int* in_sizes, int n_in,
                              void* d_out, int out_size, void* d_ws, size_t ws_size,
                              hipStream_t stream) {
    const float* x = (const float*)d_in[0];
    const float* W = (const float*)d_in[1];
    const float* b = (const float*)d_in[2];
    float* out = (float*)d_out;
    unsigned short* whi = (unsigned short*)d_ws;
    unsigned short* wlo = whi + (size_t)E * D;
    int T = in_sizes[0] / D;                  // 32768 tokens
    hipLaunchKernelGGL(wsplit_kernel, dim3((E * D) / 1024), dim3(256), 0, stream,
                       W, whi, wlo);
    hipLaunchKernelGGL(router_kernel, dim3(T / TOKS), dim3(TPB), 0, stream,
                       x, whi, wlo, b, out, T);
}